// Round 3
// baseline (978.409 us; speedup 1.0000x reference)
//
#include <hip/hip_runtime.h>
#include <hip/hip_bf16.h>
#include <math.h>

static constexpr int kN = 8192;
static constexpr int kD = 384;
static constexpr int kND = kN * kD;

typedef __attribute__((ext_vector_type(8))) short short8;
typedef __attribute__((ext_vector_type(4))) float f32x4;

// ---- bf16 helpers (bit-exact RNE) ----
__device__ __forceinline__ ushort f2bf(float f) {
  union { float f; unsigned int i; } cv; cv.f = f;
  unsigned int lsb = (cv.i >> 16) & 1u;
  unsigned int r = cv.i + 0x7fffu + lsb;
  return (ushort)(r >> 16);
}
__device__ __forceinline__ float bf2f(ushort u) {
  union { unsigned int i; float f; } cv; cv.i = ((unsigned int)u) << 16;
  return cv.f;
}
__device__ __forceinline__ f32x4 mfma_bf16(short8 a, short8 b, f32x4 c) {
  return __builtin_amdgcn_mfma_f32_16x16x32_bf16(a, b, c, 0, 0, 0);
}
// 3-term compensated product: ah*bh + ah*bl + al*bh  (error ~2^-16)
__device__ __forceinline__ f32x4 mfma3(short8 ah, short8 al, short8 bh, short8 bl, f32x4 c) {
  c = mfma_bf16(ah, bh, c);
  c = mfma_bf16(ah, bl, c);
  c = mfma_bf16(al, bh, c);
  return c;
}

// ---------------------------------------------------------------------------
// GEMM: Y = X[kN][kD] @ W[kD][kD]^T.
// MODE 0: fp32 out. MODE 1: bf16 hi/lo out. MODE 2: bf16 hi/lo transposed.
// ---------------------------------------------------------------------------
template <int MODE>
__global__ __launch_bounds__(256) void gemm_xwT(
    const float* __restrict__ X, const float* __restrict__ W,
    float* __restrict__ Y, ushort* __restrict__ Yh, ushort* __restrict__ Yl)
{
  __shared__ float Xs[64][33];
  __shared__ float WsT[32][68];
  const int tid = threadIdx.x;
  const int tx = tid & 15;
  const int ty = tid >> 4;
  const int i0 = blockIdx.x * 64;
  const int j0 = blockIdx.y * 64;
  float acc[4][4] = {};

  for (int k0 = 0; k0 < kD; k0 += 32) {
#pragma unroll
    for (int s = 0; s < 2; ++s) {
      const int f = tid + 256 * s;
      const int row = f >> 3;
      const int c4 = (f & 7) * 4;
      const float4 v = *reinterpret_cast<const float4*>(
          &X[(size_t)(i0 + row) * kD + k0 + c4]);
      Xs[row][c4 + 0] = v.x; Xs[row][c4 + 1] = v.y;
      Xs[row][c4 + 2] = v.z; Xs[row][c4 + 3] = v.w;
    }
#pragma unroll
    for (int s = 0; s < 2; ++s) {
      const int f = tid + 256 * s;
      const int col = f >> 3;
      const int c4 = (f & 7) * 4;
      const float4 v = *reinterpret_cast<const float4*>(
          &W[(size_t)(j0 + col) * kD + k0 + c4]);
      WsT[c4 + 0][col] = v.x; WsT[c4 + 1][col] = v.y;
      WsT[c4 + 2][col] = v.z; WsT[c4 + 3][col] = v.w;
    }
    __syncthreads();
#pragma unroll
    for (int kk = 0; kk < 32; ++kk) {
      const float4 b = *reinterpret_cast<const float4*>(&WsT[kk][tx * 4]);
      const float a0 = Xs[ty * 4 + 0][kk];
      const float a1 = Xs[ty * 4 + 1][kk];
      const float a2 = Xs[ty * 4 + 2][kk];
      const float a3 = Xs[ty * 4 + 3][kk];
      acc[0][0] += a0 * b.x; acc[0][1] += a0 * b.y; acc[0][2] += a0 * b.z; acc[0][3] += a0 * b.w;
      acc[1][0] += a1 * b.x; acc[1][1] += a1 * b.y; acc[1][2] += a1 * b.z; acc[1][3] += a1 * b.w;
      acc[2][0] += a2 * b.x; acc[2][1] += a2 * b.y; acc[2][2] += a2 * b.z; acc[2][3] += a2 * b.w;
      acc[3][0] += a3 * b.x; acc[3][1] += a3 * b.y; acc[3][2] += a3 * b.z; acc[3][3] += a3 * b.w;
    }
    __syncthreads();
  }
  if constexpr (MODE == 0) {
#pragma unroll
    for (int r = 0; r < 4; ++r) {
      float4 v;
      v.x = acc[r][0]; v.y = acc[r][1]; v.z = acc[r][2]; v.w = acc[r][3];
      *reinterpret_cast<float4*>(
          &Y[(size_t)(i0 + ty * 4 + r) * kD + j0 + tx * 4]) = v;
    }
  } else if constexpr (MODE == 1) {
#pragma unroll
    for (int r = 0; r < 4; ++r) {
      ushort4 h, l;
      ushort* hp = &h.x; ushort* lp = &l.x;
#pragma unroll
      for (int c = 0; c < 4; ++c) {
        const float f = acc[r][c];
        const ushort hh = f2bf(f);
        hp[c] = hh;
        lp[c] = f2bf(f - bf2f(hh));
      }
      const int oi = (i0 + ty * 4 + r) * kD + j0 + tx * 4;
      *reinterpret_cast<ushort4*>(&Yh[oi]) = h;
      *reinterpret_cast<ushort4*>(&Yl[oi]) = l;
    }
  } else {
#pragma unroll
    for (int c = 0; c < 4; ++c) {
      ushort4 h, l;
      ushort* hp = &h.x; ushort* lp = &l.x;
#pragma unroll
      for (int r = 0; r < 4; ++r) {
        const float f = acc[r][c];
        const ushort hh = f2bf(f);
        hp[r] = hh;
        lp[r] = f2bf(f - bf2f(hh));
      }
      const int oi = (j0 + tx * 4 + c) * kN + i0 + ty * 4;
      *reinterpret_cast<ushort4*>(&Yh[oi]) = h;
      *reinterpret_cast<ushort4*>(&Yl[oi]) = l;
    }
  }
}

// ---------------------------------------------------------------------------
// MFMA flash attention v3: 512 threads (8 waves), bf16x3, fp32 accumulate.
// BM=64 q-rows/block, BN=128 keys/tile, SPLIT=2 -> grid (2,128)=256 blocks.
// S^T = mfma(K,Q): wave w owns keys 16w..16w+16 of the tile, all 64 q-rows.
//   sacc[qt]: qrow=16qt+l15 (col), key=16w+4*hi4+r (row).
// PV: 6 chunks of 64 d-cols, V hi/lo double-buffered with reg-prefetch
//   (issue->commit split). Wave w: dtile 4c+(w&3), key-half (w>>2).
//   Cross-wave key-half combine via LDS at the end.
// LDS: Qhi 49K | P hi/lo 34.8K | V dbuf hi/lo 69.6K | mlb 4K  = 155K -> 1
// block/CU, 8 waves/CU (2/SIMD).
// ---------------------------------------------------------------------------
static constexpr int SPLITf = 2;
static constexpr int KEYSf = kN / SPLITf;  // 4096 -> 32 tiles of 128

static constexpr int OFF_PH = 25088;            // ushort offsets into LDSU
static constexpr int OFF_PL = 25088 + 8704;     // 33792
static constexpr int OFF_V  = 33792 + 8704;     // 42496 ; V(buf,hilo)=OFF_V+buf*17408+hilo*8704

__global__ __launch_bounds__(512, 2) void flash_mfma(
    const ushort* __restrict__ Qh, const ushort* __restrict__ Ql,
    const ushort* __restrict__ Kh, const ushort* __restrict__ Kl,
    const ushort* __restrict__ VTh, const ushort* __restrict__ VTl,
    float* __restrict__ Opart, float* __restrict__ ml)
{
  __shared__ ushort LDSU[77312];   // 154624 B
  __shared__ float MLB[1024];      // m: [0,512), l: [512,1024)

  const int tid = threadIdx.x;
  const int w = tid >> 6;
  const int lane = tid & 63;
  const int l15 = lane & 15;
  const int hi4 = lane >> 4;
  const int sp = blockIdx.x;
  const int i0 = blockIdx.y * 64;
  const int kg0 = sp * KEYSf;

  // ---- stage Q-hi once: rows 0..63, stride 392 ushorts ----
  {
    const int row = tid >> 3;
    const int sg = (tid & 7) * 48;
    const ushort* s = Qh + (size_t)(i0 + row) * kD + sg;
    ushort* d = LDSU + row * 392 + sg;
#pragma unroll
    for (int u = 0; u < 6; ++u)
      *reinterpret_cast<uint4*>(d + 8 * u) =
          *reinterpret_cast<const uint4*>(s + 8 * u);
  }

  const f32x4 zf = {0.f, 0.f, 0.f, 0.f};
  f32x4 o[4][6];
#pragma unroll
  for (int qt = 0; qt < 4; ++qt)
#pragma unroll
    for (int c = 0; c < 6; ++c) o[qt][c] = zf;
  float m_run[4], l_run[4];
#pragma unroll
  for (int qt = 0; qt < 4; ++qt) { m_run[qt] = -INFINITY; l_run[qt] = 0.f; }

  // V staging thread mapping (chunk = 64 dcols x 128 keys)
  const int vrow = tid >> 3;          // dcol within chunk
  const int vseg = (tid & 7) * 16;    // ushort offset within 128-key row
  uint4 vh0, vh1, vl0, vl1;

  const int dtl = w & 3;              // PV d-tile within chunk
  const int ks0 = (w >> 2) * 2;       // PV key-half: ksv in {ks0, ks0+1}

  __syncthreads();

  for (int kb = 0; kb < KEYSf / 128; ++kb) {
    const int kg = kg0 + kb * 128;

    // ---- issue V chunk 0 (in flight through S phase) ----
    {
      const size_t g = (size_t)vrow * kN + kg + vseg;
      vh0 = *reinterpret_cast<const uint4*>(VTh + g);
      vh1 = *reinterpret_cast<const uint4*>(VTh + g + 8);
      vl0 = *reinterpret_cast<const uint4*>(VTl + g);
      vl1 = *reinterpret_cast<const uint4*>(VTl + g + 8);
    }

    // ---- S phase ----
    f32x4 sacc[4];
#pragma unroll
    for (int qt = 0; qt < 4; ++qt) sacc[qt] = zf;
    const size_t kbase = (size_t)(kg + 16 * w + l15) * kD + 8 * hi4;
    const size_t qlb = (size_t)(i0 + l15) * kD + 8 * hi4;
#pragma unroll 6
    for (int ks = 0; ks < 12; ++ks) {
      const int d0 = 32 * ks;
      const short8 kh = *reinterpret_cast<const short8*>(Kh + kbase + d0);
      const short8 kl = *reinterpret_cast<const short8*>(Kl + kbase + d0);
#pragma unroll
      for (int qt = 0; qt < 4; ++qt) {
        const short8 qh = *reinterpret_cast<const short8*>(
            LDSU + (16 * qt + l15) * 392 + d0 + 8 * hi4);
        const short8 ql = *reinterpret_cast<const short8*>(
            Ql + qlb + (size_t)6144 * qt + d0);
        sacc[qt] = mfma3(kh, kl, qh, ql, sacc[qt]);
      }
    }

    // ---- online softmax ----
    float mt4[4];
#pragma unroll
    for (int qt = 0; qt < 4; ++qt) {
      float mt = fmaxf(fmaxf(sacc[qt][0], sacc[qt][1]),
                       fmaxf(sacc[qt][2], sacc[qt][3]));
      mt = fmaxf(mt, __shfl_xor(mt, 16, 64));
      mt = fmaxf(mt, __shfl_xor(mt, 32, 64));
      mt4[qt] = mt;
    }
    if (lane < 16) {
#pragma unroll
      for (int qt = 0; qt < 4; ++qt) MLB[w * 64 + qt * 16 + l15] = mt4[qt];
    }
    __syncthreads();  // B1
    float sc[4];
#pragma unroll
    for (int qt = 0; qt < 4; ++qt) {
      float Mt = MLB[qt * 16 + l15];
#pragma unroll
      for (int w2 = 1; w2 < 8; ++w2)
        Mt = fmaxf(Mt, MLB[w2 * 64 + qt * 16 + l15]);
      const float mnew = fmaxf(m_run[qt], Mt);
      sc[qt] = __expf(m_run[qt] - mnew);
      m_run[qt] = mnew;
      const float p0 = __expf(sacc[qt][0] - mnew);
      const float p1 = __expf(sacc[qt][1] - mnew);
      const float p2 = __expf(sacc[qt][2] - mnew);
      const float p3 = __expf(sacc[qt][3] - mnew);
      float ls = (p0 + p1) + (p2 + p3);
      ls += __shfl_xor(ls, 16, 64);
      ls += __shfl_xor(ls, 32, 64);
      if (lane < 16) MLB[512 + w * 64 + qt * 16 + l15] = ls;
      // pack P -> bf16 hi/lo, one b64 write each
      const ushort h0 = f2bf(p0), h1 = f2bf(p1), h2 = f2bf(p2), h3 = f2bf(p3);
      const ushort g0 = f2bf(p0 - bf2f(h0)), g1 = f2bf(p1 - bf2f(h1));
      const ushort g2 = f2bf(p2 - bf2f(h2)), g3 = f2bf(p3 - bf2f(h3));
      uint2 HH, LL;
      HH.x = (unsigned int)h0 | ((unsigned int)h1 << 16);
      HH.y = (unsigned int)h2 | ((unsigned int)h3 << 16);
      LL.x = (unsigned int)g0 | ((unsigned int)g1 << 16);
      LL.y = (unsigned int)g2 | ((unsigned int)g3 << 16);
      const int pi = (16 * qt + l15) * 136 + 16 * w + 4 * hi4;
      *reinterpret_cast<uint2*>(LDSU + OFF_PH + pi) = HH;
      *reinterpret_cast<uint2*>(LDSU + OFF_PL + pi) = LL;
      // rescale O (row of o = qrow 16qt+4*hi4+r)
#pragma unroll
      for (int r = 0; r < 4; ++r) {
        const float scr_ = __shfl(sc[qt], 4 * hi4 + r, 64);
#pragma unroll
        for (int c = 0; c < 6; ++c) o[qt][c][r] *= scr_;
      }
    }
    __syncthreads();  // B2: P + mlb_l ready
#pragma unroll
    for (int qt = 0; qt < 4; ++qt) {
      float acc = MLB[512 + qt * 16 + l15];
#pragma unroll
      for (int w2 = 1; w2 < 8; ++w2) acc += MLB[512 + w2 * 64 + qt * 16 + l15];
      l_run[qt] = l_run[qt] * sc[qt] + acc;
    }

    // ---- PV: 6 chunks, dbuf, reg-prefetch staging ----
#pragma unroll
    for (int c = 0; c < 6; ++c) {
      {  // commit prefetched chunk c into buf c&1
        ushort* d = LDSU + OFF_V + (c & 1) * 17408 + vrow * 136 + vseg;
        *reinterpret_cast<uint4*>(d) = vh0;
        *reinterpret_cast<uint4*>(d + 8) = vh1;
        *reinterpret_cast<uint4*>(d + 8704) = vl0;
        *reinterpret_cast<uint4*>(d + 8712) = vl1;
      }
      __syncthreads();
      if (c < 5) {  // issue chunk c+1
        const size_t g = (size_t)(64 * (c + 1) + vrow) * kN + kg + vseg;
        vh0 = *reinterpret_cast<const uint4*>(VTh + g);
        vh1 = *reinterpret_cast<const uint4*>(VTh + g + 8);
        vl0 = *reinterpret_cast<const uint4*>(VTl + g);
        vl1 = *reinterpret_cast<const uint4*>(VTl + g + 8);
      }
#pragma unroll
      for (int ki = 0; ki < 2; ++ki) {
        const int ksv = ks0 + ki;
        const int vb =
            OFF_V + (c & 1) * 17408 + (16 * dtl + l15) * 136 + 32 * ksv + 8 * hi4;
        const short8 vfh = *reinterpret_cast<const short8*>(LDSU + vb);
        const short8 vfl = *reinterpret_cast<const short8*>(LDSU + vb + 8704);
#pragma unroll
        for (int qt = 0; qt < 4; ++qt) {
          const int pb = (16 * qt + l15) * 136 + 32 * ksv + 8 * hi4;
          const short8 pfh = *reinterpret_cast<const short8*>(LDSU + OFF_PH + pb);
          const short8 pfl = *reinterpret_cast<const short8*>(LDSU + OFF_PL + pb);
          o[qt][c] = mfma3(pfh, pfl, vfh, vfl, o[qt][c]);
        }
      }
    }
  }

  // ---- combine key-halves (waves 4-7 -> waves 0-3) via LDS reuse ----
  __syncthreads();
  float* scr = reinterpret_cast<float*>(LDSU + OFF_PH);
  if (w >= 4) {
    const int base = ((w - 4) * 64 + lane) * 96;
#pragma unroll
    for (int qt = 0; qt < 4; ++qt)
#pragma unroll
      for (int c = 0; c < 6; ++c)
        *reinterpret_cast<f32x4*>(scr + base + (qt * 6 + c) * 4) = o[qt][c];
  }
  __syncthreads();
  if (w < 4) {
    const int base = (w * 64 + lane) * 96;
#pragma unroll
    for (int qt = 0; qt < 4; ++qt)
#pragma unroll
      for (int c = 0; c < 6; ++c)
        o[qt][c] += *reinterpret_cast<f32x4*>(scr + base + (qt * 6 + c) * 4);
#pragma unroll
    for (int qt = 0; qt < 4; ++qt)
#pragma unroll
      for (int c = 0; c < 6; ++c)
#pragma unroll
        for (int r = 0; r < 4; ++r)
          Opart[(size_t)sp * kND + (i0 + 16 * qt + 4 * hi4 + r) * kD +
                16 * (4 * c + w) + l15] = o[qt][c][r];
  }
  if (w == 0 && lane < 16) {
#pragma unroll
    for (int qt = 0; qt < 4; ++qt) {
      const int mi = (sp * kN + i0 + 16 * qt + l15) * 2;
      ml[mi] = m_run[qt];
      ml[mi + 1] = l_run[qt];
    }
  }
}

// ---------------------------------------------------------------------------
// Merge 2 key-split partials
// ---------------------------------------------------------------------------
__global__ __launch_bounds__(256) void merge_kernel(
    const float* __restrict__ Opart, const float* __restrict__ ml,
    float* __restrict__ O)
{
  const size_t idx = (size_t)blockIdx.x * 256 + threadIdx.x;
  const size_t i = idx / kD;
  const float m0 = ml[i * 2];
  const float l0 = ml[i * 2 + 1];
  const float m1 = ml[((size_t)kN + i) * 2];
  const float l1 = ml[((size_t)kN + i) * 2 + 1];
  const float m = fmaxf(m0, m1);
  const float e0 = expf(m0 - m);
  const float e1 = expf(m1 - m);
  const float inv = 1.0f / (e0 * l0 + e1 * l1);
  O[idx] = (e0 * Opart[idx] + e1 * Opart[(size_t)kND + idx]) * inv;
}

// ---------------------------------------------------------------------------
// Layer-2 helpers (only last row of layer 2 needed)
// ---------------------------------------------------------------------------
__global__ __launch_bounds__(64) void qrow_kernel(
    const float* __restrict__ h1, const float* __restrict__ Wq,
    float* __restrict__ q2)
{
  const int j = blockIdx.x;
  const int lane = threadIdx.x;
  const float* hr = h1 + (size_t)(kN - 1) * kD;
  float acc = 0.f;
  for (int d = lane; d < kD; d += 64) acc += hr[d] * Wq[(size_t)j * kD + d];
#pragma unroll
  for (int off = 32; off > 0; off >>= 1) acc += __shfl_xor(acc, off, 64);
  if (lane == 0) q2[j] = acc;
}

__global__ __launch_bounds__(256) void logits_kernel(
    const float* __restrict__ Kt2, const float* __restrict__ q2,
    float* __restrict__ lg)
{
  const int wave = threadIdx.x >> 6;
  const int lane = threadIdx.x & 63;
  const int j = blockIdx.x * 4 + wave;
  float acc = 0.f;
#pragma unroll
  for (int t = 0; t < kD / 64; ++t) {
    const int d = lane + t * 64;
    acc += Kt2[(size_t)j * kD + d] * q2[d];
  }
#pragma unroll
  for (int off = 32; off > 0; off >>= 1) acc += __shfl_xor(acc, off, 64);
  if (lane == 0) lg[j] = acc;
}

__global__ __launch_bounds__(1024) void smax_kernel(
    const float* __restrict__ lg, float* __restrict__ wgt)
{
  __shared__ float red[16];
  const int t = threadIdx.x;
  const int wave = t >> 6;
  const int lane = t & 63;
  float v[8];
  float mx = -INFINITY;
#pragma unroll
  for (int s = 0; s < 8; ++s) {
    v[s] = lg[t + 1024 * s];
    mx = fmaxf(mx, v[s]);
  }
#pragma unroll
  for (int off = 32; off > 0; off >>= 1) mx = fmaxf(mx, __shfl_xor(mx, off, 64));
  if (lane == 0) red[wave] = mx;
  __syncthreads();
  if (t == 0) {
    float m = red[0];
    for (int i = 1; i < 16; ++i) m = fmaxf(m, red[i]);
    red[0] = m;
  }
  __syncthreads();
  const float m = red[0];
  __syncthreads();
  float sum = 0.f;
#pragma unroll
  for (int s = 0; s < 8; ++s) {
    v[s] = expf(v[s] - m);
    sum += v[s];
  }
#pragma unroll
  for (int off = 32; off > 0; off >>= 1) sum += __shfl_xor(sum, off, 64);
  if (lane == 0) red[wave] = sum;
  __syncthreads();
  if (t == 0) {
    float S = 0.f;
    for (int i = 0; i < 16; ++i) S += red[i];
    red[0] = S;
  }
  __syncthreads();
  const float invS = 1.0f / red[0];
#pragma unroll
  for (int s = 0; s < 8; ++s) wgt[t + 1024 * s] = v[s] * invS;
}

__global__ __launch_bounds__(384) void wsum_kernel(
    const float* __restrict__ wgt, const float* __restrict__ Vt2,
    float* __restrict__ part)
{
  __shared__ float wl[256];
  const int b = blockIdx.x;
  const int t = threadIdx.x;
  if (t < 256) wl[t] = wgt[b * 256 + t];
  __syncthreads();
  const float* Vp = Vt2 + (size_t)b * 256 * kD;
  float acc = 0.f;
  for (int j = 0; j < 256; ++j) acc += wl[j] * Vp[(size_t)j * kD + t];
  part[b * kD + t] = acc;
}

__global__ __launch_bounds__(384) void final_kernel(
    const float* __restrict__ part, const float* __restrict__ ffws,
    float* __restrict__ out)
{
  __shared__ float red[6];
  const int t = threadIdx.x;
  const int wave = t >> 6;
  const int lane = t & 63;
  float z = 0.f;
#pragma unroll
  for (int b = 0; b < 32; ++b) z += part[b * kD + t];
  float val = z * ffws[t];
#pragma unroll
  for (int off = 32; off > 0; off >>= 1) val += __shfl_xor(val, off, 64);
  if (lane == 0) red[wave] = val;
  __syncthreads();
  if (t == 0) {
    float s = red[0];
    for (int i = 1; i < 6; ++i) s += red[i];
    out[0] = 1.0f / (1.0f + expf(-s));
  }
}

// ---------------------------------------------------------------------------
extern "C" void kernel_launch(void* const* d_in, const int* in_sizes, int n_in,
                              void* d_out, int out_size, void* d_ws, size_t ws_size,
                              hipStream_t stream) {
  const float* x    = (const float*)d_in[0];
  const float* Wq   = (const float*)d_in[1];
  const float* Wk   = (const float*)d_in[2];
  const float* Wv   = (const float*)d_in[3];
  const float* ffws = (const float*)d_in[4];
  float* out = (float*)d_out;
  char* wsb = (char*)d_ws;

  ushort* Qh  = (ushort*)wsb;
  ushort* Ql  = Qh + kND;
  ushort* Kh  = Ql + kND;
  ushort* Kl  = Kh + kND;
  ushort* VTh = Kl + kND;
  ushort* VTl = VTh + kND;
  float* Opart = (float*)(wsb + 6 * (size_t)kND * 2);
  float* ml    = Opart + 2 * (size_t)kND;
  // phase-2 overlays (flash buffers dead):
  float* Kt2 = (float*)wsb;                         // over Qh/Ql
  float* Vt2 = (float*)(wsb + 2 * (size_t)kND * 2); // over Kh/Kl
  float* h1  = (float*)(wsb + 4 * (size_t)kND * 2); // over VTh/VTl
  float* q2  = (float*)(wsb + 6 * (size_t)kND * 2); // over Opart
  float* lg  = q2 + kD;
  float* wgt = lg + kN;
  float* part = wgt + kN;

  const dim3 gg(kN / 64, kD / 64);
  gemm_xwT<1><<<gg, 256, 0, stream>>>(x, Wq, nullptr, Qh, Ql);
  gemm_xwT<1><<<gg, 256, 0, stream>>>(x, Wk, nullptr, Kh, Kl);
  gemm_xwT<2><<<gg, 256, 0, stream>>>(x, Wv, nullptr, VTh, VTl);
  flash_mfma<<<dim3(SPLITf, kN / 64), 512, 0, stream>>>(
      Qh, Ql, Kh, Kl, VTh, VTl, Opart, ml);
  merge_kernel<<<(kN * kD) / 256, 256, 0, stream>>>(Opart, ml, h1);
  gemm_xwT<0><<<gg, 256, 0, stream>>>(h1, Wk, Kt2, nullptr, nullptr);
  gemm_xwT<0><<<gg, 256, 0, stream>>>(h1, Wv, Vt2, nullptr, nullptr);
  qrow_kernel<<<kD, 64, 0, stream>>>(h1, Wq, q2);
  logits_kernel<<<kN / 4, 256, 0, stream>>>(Kt2, q2, lg);
  smax_kernel<<<1, 1024, 0, stream>>>(lg, wgt);
  wsum_kernel<<<32, 384, 0, stream>>>(wgt, Vt2, part);
  final_kernel<<<1, 384, 0, stream>>>(part, ffws, out);
}

// Round 4
// 614.519 us; speedup vs baseline: 1.5922x; 1.5922x over previous
//
#include <hip/hip_runtime.h>
#include <hip/hip_bf16.h>
#include <math.h>

static constexpr int kN = 8192;
static constexpr int kD = 384;
static constexpr int kND = kN * kD;

typedef __attribute__((ext_vector_type(8))) short short8;
typedef __attribute__((ext_vector_type(4))) float f32x4;

// ---- bf16 helpers (bit-exact RNE) ----
__device__ __forceinline__ ushort f2bf(float f) {
  union { float f; unsigned int i; } cv; cv.f = f;
  unsigned int lsb = (cv.i >> 16) & 1u;
  unsigned int r = cv.i + 0x7fffu + lsb;
  return (ushort)(r >> 16);
}
__device__ __forceinline__ float bf2f(ushort u) {
  union { unsigned int i; float f; } cv; cv.i = ((unsigned int)u) << 16;
  return cv.f;
}
__device__ __forceinline__ f32x4 mfma_bf16(short8 a, short8 b, f32x4 c) {
  return __builtin_amdgcn_mfma_f32_16x16x32_bf16(a, b, c, 0, 0, 0);
}
// 3-term compensated product: ah*bh + ah*bl + al*bh  (error ~2^-16)
__device__ __forceinline__ f32x4 mfma3(short8 ah, short8 al, short8 bh, short8 bl, f32x4 c) {
  c = mfma_bf16(ah, bh, c);
  c = mfma_bf16(ah, bl, c);
  c = mfma_bf16(al, bh, c);
  return c;
}

// ---------------------------------------------------------------------------
// GEMM: Y = X[kN][kD] @ W[kD][kD]^T.
// MODE 0: fp32 out. MODE 1: bf16 hi/lo out. MODE 2: bf16 hi/lo transposed.
// ---------------------------------------------------------------------------
template <int MODE>
__global__ __launch_bounds__(256) void gemm_xwT(
    const float* __restrict__ X, const float* __restrict__ W,
    float* __restrict__ Y, ushort* __restrict__ Yh, ushort* __restrict__ Yl)
{
  __shared__ float Xs[64][33];
  __shared__ float WsT[32][68];
  const int tid = threadIdx.x;
  const int tx = tid & 15;
  const int ty = tid >> 4;
  const int i0 = blockIdx.x * 64;
  const int j0 = blockIdx.y * 64;
  float acc[4][4] = {};

  for (int k0 = 0; k0 < kD; k0 += 32) {
#pragma unroll
    for (int s = 0; s < 2; ++s) {
      const int f = tid + 256 * s;
      const int row = f >> 3;
      const int c4 = (f & 7) * 4;
      const float4 v = *reinterpret_cast<const float4*>(
          &X[(size_t)(i0 + row) * kD + k0 + c4]);
      Xs[row][c4 + 0] = v.x; Xs[row][c4 + 1] = v.y;
      Xs[row][c4 + 2] = v.z; Xs[row][c4 + 3] = v.w;
    }
#pragma unroll
    for (int s = 0; s < 2; ++s) {
      const int f = tid + 256 * s;
      const int col = f >> 3;
      const int c4 = (f & 7) * 4;
      const float4 v = *reinterpret_cast<const float4*>(
          &W[(size_t)(j0 + col) * kD + k0 + c4]);
      WsT[c4 + 0][col] = v.x; WsT[c4 + 1][col] = v.y;
      WsT[c4 + 2][col] = v.z; WsT[c4 + 3][col] = v.w;
    }
    __syncthreads();
#pragma unroll
    for (int kk = 0; kk < 32; ++kk) {
      const float4 b = *reinterpret_cast<const float4*>(&WsT[kk][tx * 4]);
      const float a0 = Xs[ty * 4 + 0][kk];
      const float a1 = Xs[ty * 4 + 1][kk];
      const float a2 = Xs[ty * 4 + 2][kk];
      const float a3 = Xs[ty * 4 + 3][kk];
      acc[0][0] += a0 * b.x; acc[0][1] += a0 * b.y; acc[0][2] += a0 * b.z; acc[0][3] += a0 * b.w;
      acc[1][0] += a1 * b.x; acc[1][1] += a1 * b.y; acc[1][2] += a1 * b.z; acc[1][3] += a1 * b.w;
      acc[2][0] += a2 * b.x; acc[2][1] += a2 * b.y; acc[2][2] += a2 * b.z; acc[2][3] += a2 * b.w;
      acc[3][0] += a3 * b.x; acc[3][1] += a3 * b.y; acc[3][2] += a3 * b.z; acc[3][3] += a3 * b.w;
    }
    __syncthreads();
  }
  if constexpr (MODE == 0) {
#pragma unroll
    for (int r = 0; r < 4; ++r) {
      float4 v;
      v.x = acc[r][0]; v.y = acc[r][1]; v.z = acc[r][2]; v.w = acc[r][3];
      *reinterpret_cast<float4*>(
          &Y[(size_t)(i0 + ty * 4 + r) * kD + j0 + tx * 4]) = v;
    }
  } else if constexpr (MODE == 1) {
#pragma unroll
    for (int r = 0; r < 4; ++r) {
      ushort4 h, l;
      ushort* hp = &h.x; ushort* lp = &l.x;
#pragma unroll
      for (int c = 0; c < 4; ++c) {
        const float f = acc[r][c];
        const ushort hh = f2bf(f);
        hp[c] = hh;
        lp[c] = f2bf(f - bf2f(hh));
      }
      const int oi = (i0 + ty * 4 + r) * kD + j0 + tx * 4;
      *reinterpret_cast<ushort4*>(&Yh[oi]) = h;
      *reinterpret_cast<ushort4*>(&Yl[oi]) = l;
    }
  } else {
#pragma unroll
    for (int c = 0; c < 4; ++c) {
      ushort4 h, l;
      ushort* hp = &h.x; ushort* lp = &l.x;
#pragma unroll
      for (int r = 0; r < 4; ++r) {
        const float f = acc[r][c];
        const ushort hh = f2bf(f);
        hp[r] = hh;
        lp[r] = f2bf(f - bf2f(hh));
      }
      const int oi = (j0 + tx * 4 + c) * kN + i0 + ty * 4;
      *reinterpret_cast<ushort4*>(&Yh[oi]) = h;
      *reinterpret_cast<ushort4*>(&Yl[oi]) = l;
    }
  }
}

// ---------------------------------------------------------------------------
// MFMA flash attention v4: 512 threads (8 waves), 2 barriers/tile.
// BM=64 q-rows/block, BN=128 keys/tile, SPLIT=2 -> grid (2,128)=256 blocks.
// S^T = mfma3(K,Q): wave w owns keys [16w,16w+16), all 64 q-rows.
//   sacc[qt]: key=16w+4*hi4+r (row), qrow=16qt+l15 (col).
// Q-hi AND Q-lo staged once in LDS; K hi/lo direct from global (L2).
// P stored hi-only in LDS; PV = ph*vh + ph*vl with V-frags direct from
// global VT (wave w owns d-cols [48w,48w+48) -> private, no LDS, no barrier).
// LDS: Qh 49K | Ql 49K | P-hi 17.4K | MLB 4K = 122K -> 1 block/CU, 8 waves.
// ---------------------------------------------------------------------------
static constexpr int SPLITf = 2;
static constexpr int KEYSf = kN / SPLITf;  // 4096 -> 32 tiles of 128

static constexpr int OFF_QH = 0;       // ushort offsets into LDSU
static constexpr int OFF_QL = 25088;   // 64*392
static constexpr int OFF_P  = 50176;   // + 64*392

__global__ __launch_bounds__(512, 2) void flash_mfma(
    const ushort* __restrict__ Qh, const ushort* __restrict__ Ql,
    const ushort* __restrict__ Kh, const ushort* __restrict__ Kl,
    const ushort* __restrict__ VTh, const ushort* __restrict__ VTl,
    float* __restrict__ Opart, float* __restrict__ ml)
{
  __shared__ ushort LDSU[58880];   // 117760 B
  __shared__ float MLB[1024];      // m: [0,512), l: [512,1024)

  const int tid = threadIdx.x;
  const int w = tid >> 6;
  const int lane = tid & 63;
  const int l15 = lane & 15;
  const int hi4 = lane >> 4;
  const int sp = blockIdx.x;
  const int i0 = blockIdx.y * 64;
  const int kg0 = sp * KEYSf;

  // ---- stage Q-hi + Q-lo once: rows 0..63, stride 392 ushorts ----
  {
    const int row = tid >> 3;
    const int sg = (tid & 7) * 48;
    const ushort* sh = Qh + (size_t)(i0 + row) * kD + sg;
    const ushort* sl = Ql + (size_t)(i0 + row) * kD + sg;
    ushort* dh = LDSU + OFF_QH + row * 392 + sg;
    ushort* dl = LDSU + OFF_QL + row * 392 + sg;
#pragma unroll
    for (int u = 0; u < 6; ++u) {
      *reinterpret_cast<uint4*>(dh + 8 * u) =
          *reinterpret_cast<const uint4*>(sh + 8 * u);
      *reinterpret_cast<uint4*>(dl + 8 * u) =
          *reinterpret_cast<const uint4*>(sl + 8 * u);
    }
  }

  const f32x4 zf = {0.f, 0.f, 0.f, 0.f};
  f32x4 o[4][3];
#pragma unroll
  for (int qt = 0; qt < 4; ++qt)
#pragma unroll
    for (int c = 0; c < 3; ++c) o[qt][c] = zf;
  float m_run[4], l_run[4];
#pragma unroll
  for (int qt = 0; qt < 4; ++qt) { m_run[qt] = -INFINITY; l_run[qt] = 0.f; }

  __syncthreads();

  for (int kb = 0; kb < KEYSf / 128; ++kb) {
    const int kg = kg0 + kb * 128;

    // ---- S phase: K hi/lo direct from global, Q hi/lo from LDS ----
    f32x4 sacc[4];
#pragma unroll
    for (int qt = 0; qt < 4; ++qt) sacc[qt] = zf;
    const size_t kbase = (size_t)(kg + 16 * w + l15) * kD + 8 * hi4;
#pragma unroll 6
    for (int ks = 0; ks < 12; ++ks) {
      const int d0 = 32 * ks;
      const short8 kh = *reinterpret_cast<const short8*>(Kh + kbase + d0);
      const short8 kl = *reinterpret_cast<const short8*>(Kl + kbase + d0);
#pragma unroll
      for (int qt = 0; qt < 4; ++qt) {
        const int qoff = (16 * qt + l15) * 392 + d0 + 8 * hi4;
        const short8 qh = *reinterpret_cast<const short8*>(LDSU + OFF_QH + qoff);
        const short8 ql = *reinterpret_cast<const short8*>(LDSU + OFF_QL + qoff);
        sacc[qt] = mfma3(kh, kl, qh, ql, sacc[qt]);
      }
    }

    // ---- online softmax ----
    float mt4[4];
#pragma unroll
    for (int qt = 0; qt < 4; ++qt) {
      float mt = fmaxf(fmaxf(sacc[qt][0], sacc[qt][1]),
                       fmaxf(sacc[qt][2], sacc[qt][3]));
      mt = fmaxf(mt, __shfl_xor(mt, 16, 64));
      mt = fmaxf(mt, __shfl_xor(mt, 32, 64));
      mt4[qt] = mt;
    }
    if (lane < 16) {
#pragma unroll
      for (int qt = 0; qt < 4; ++qt) MLB[w * 64 + qt * 16 + l15] = mt4[qt];
    }
    __syncthreads();  // B1
    float sc[4];
#pragma unroll
    for (int qt = 0; qt < 4; ++qt) {
      float Mt = MLB[qt * 16 + l15];
#pragma unroll
      for (int w2 = 1; w2 < 8; ++w2)
        Mt = fmaxf(Mt, MLB[w2 * 64 + qt * 16 + l15]);
      const float mnew = fmaxf(m_run[qt], Mt);
      sc[qt] = __expf(m_run[qt] - mnew);
      m_run[qt] = mnew;
      const float p0 = __expf(sacc[qt][0] - mnew);
      const float p1 = __expf(sacc[qt][1] - mnew);
      const float p2 = __expf(sacc[qt][2] - mnew);
      const float p3 = __expf(sacc[qt][3] - mnew);
      float ls = (p0 + p1) + (p2 + p3);
      ls += __shfl_xor(ls, 16, 64);
      ls += __shfl_xor(ls, 32, 64);
      if (lane < 16) MLB[512 + w * 64 + qt * 16 + l15] = ls;
      // pack P -> bf16 hi only, one b64 write
      uint2 HH;
      HH.x = (unsigned int)f2bf(p0) | ((unsigned int)f2bf(p1) << 16);
      HH.y = (unsigned int)f2bf(p2) | ((unsigned int)f2bf(p3) << 16);
      const int pi = (16 * qt + l15) * 136 + 16 * w + 4 * hi4;
      *reinterpret_cast<uint2*>(LDSU + OFF_P + pi) = HH;
      // rescale O (row of o = qrow 16qt+4*hi4+r)
#pragma unroll
      for (int r = 0; r < 4; ++r) {
        const float scr_ = __shfl(sc[qt], 4 * hi4 + r, 64);
#pragma unroll
        for (int c = 0; c < 3; ++c) o[qt][c][r] *= scr_;
      }
    }
    __syncthreads();  // B2: P + mlb_l ready
#pragma unroll
    for (int qt = 0; qt < 4; ++qt) {
      float acc = MLB[512 + qt * 16 + l15];
#pragma unroll
      for (int w2 = 1; w2 < 8; ++w2) acc += MLB[512 + w2 * 64 + qt * 16 + l15];
      l_run[qt] = l_run[qt] * sc[qt] + acc;
    }

    // ---- PV: barrier-free; wave w owns d-cols [48w, 48w+48) ----
#pragma unroll
    for (int ksv = 0; ksv < 4; ++ksv) {
      short8 pf0 = *reinterpret_cast<const short8*>(
          LDSU + OFF_P + (l15)*136 + 32 * ksv + 8 * hi4);
      short8 pf1 = *reinterpret_cast<const short8*>(
          LDSU + OFF_P + (16 + l15) * 136 + 32 * ksv + 8 * hi4);
      short8 pf2 = *reinterpret_cast<const short8*>(
          LDSU + OFF_P + (32 + l15) * 136 + 32 * ksv + 8 * hi4);
      short8 pf3 = *reinterpret_cast<const short8*>(
          LDSU + OFF_P + (48 + l15) * 136 + 32 * ksv + 8 * hi4);
#pragma unroll
      for (int c = 0; c < 3; ++c) {
        const size_t g =
            (size_t)(48 * w + 16 * c + l15) * kN + kg + 32 * ksv + 8 * hi4;
        const short8 vfh = *reinterpret_cast<const short8*>(VTh + g);
        const short8 vfl = *reinterpret_cast<const short8*>(VTl + g);
        o[0][c] = mfma_bf16(pf0, vfh, o[0][c]);
        o[0][c] = mfma_bf16(pf0, vfl, o[0][c]);
        o[1][c] = mfma_bf16(pf1, vfh, o[1][c]);
        o[1][c] = mfma_bf16(pf1, vfl, o[1][c]);
        o[2][c] = mfma_bf16(pf2, vfh, o[2][c]);
        o[2][c] = mfma_bf16(pf2, vfl, o[2][c]);
        o[3][c] = mfma_bf16(pf3, vfh, o[3][c]);
        o[3][c] = mfma_bf16(pf3, vfl, o[3][c]);
      }
    }
  }

  // ---- write unnormalized partials + (m,l); waves own disjoint d-cols ----
#pragma unroll
  for (int qt = 0; qt < 4; ++qt)
#pragma unroll
    for (int c = 0; c < 3; ++c)
#pragma unroll
      for (int r = 0; r < 4; ++r)
        Opart[(size_t)sp * kND + (i0 + 16 * qt + 4 * hi4 + r) * kD +
              48 * w + 16 * c + l15] = o[qt][c][r];
  if (w == 0 && lane < 16) {
#pragma unroll
    for (int qt = 0; qt < 4; ++qt) {
      const int mi = (sp * kN + i0 + 16 * qt + l15) * 2;
      ml[mi] = m_run[qt];
      ml[mi + 1] = l_run[qt];
    }
  }
}

// ---------------------------------------------------------------------------
// Merge 2 key-split partials
// ---------------------------------------------------------------------------
__global__ __launch_bounds__(256) void merge_kernel(
    const float* __restrict__ Opart, const float* __restrict__ ml,
    float* __restrict__ O)
{
  const size_t idx = (size_t)blockIdx.x * 256 + threadIdx.x;
  const size_t i = idx / kD;
  const float m0 = ml[i * 2];
  const float l0 = ml[i * 2 + 1];
  const float m1 = ml[((size_t)kN + i) * 2];
  const float l1 = ml[((size_t)kN + i) * 2 + 1];
  const float m = fmaxf(m0, m1);
  const float e0 = expf(m0 - m);
  const float e1 = expf(m1 - m);
  const float inv = 1.0f / (e0 * l0 + e1 * l1);
  O[idx] = (e0 * Opart[idx] + e1 * Opart[(size_t)kND + idx]) * inv;
}

// ---------------------------------------------------------------------------
// Layer-2 helpers (only last row of layer 2 needed)
// ---------------------------------------------------------------------------
__global__ __launch_bounds__(64) void qrow_kernel(
    const float* __restrict__ h1, const float* __restrict__ Wq,
    float* __restrict__ q2)
{
  const int j = blockIdx.x;
  const int lane = threadIdx.x;
  const float* hr = h1 + (size_t)(kN - 1) * kD;
  float acc = 0.f;
  for (int d = lane; d < kD; d += 64) acc += hr[d] * Wq[(size_t)j * kD + d];
#pragma unroll
  for (int off = 32; off > 0; off >>= 1) acc += __shfl_xor(acc, off, 64);
  if (lane == 0) q2[j] = acc;
}

__global__ __launch_bounds__(256) void logits_kernel(
    const float* __restrict__ Kt2, const float* __restrict__ q2,
    float* __restrict__ lg)
{
  const int wave = threadIdx.x >> 6;
  const int lane = threadIdx.x & 63;
  const int j = blockIdx.x * 4 + wave;
  float acc = 0.f;
#pragma unroll
  for (int t = 0; t < kD / 64; ++t) {
    const int d = lane + t * 64;
    acc += Kt2[(size_t)j * kD + d] * q2[d];
  }
#pragma unroll
  for (int off = 32; off > 0; off >>= 1) acc += __shfl_xor(acc, off, 64);
  if (lane == 0) lg[j] = acc;
}

__global__ __launch_bounds__(1024) void smax_kernel(
    const float* __restrict__ lg, float* __restrict__ wgt)
{
  __shared__ float red[16];
  const int t = threadIdx.x;
  const int wave = t >> 6;
  const int lane = t & 63;
  float v[8];
  float mx = -INFINITY;
#pragma unroll
  for (int s = 0; s < 8; ++s) {
    v[s] = lg[t + 1024 * s];
    mx = fmaxf(mx, v[s]);
  }
#pragma unroll
  for (int off = 32; off > 0; off >>= 1) mx = fmaxf(mx, __shfl_xor(mx, off, 64));
  if (lane == 0) red[wave] = mx;
  __syncthreads();
  if (t == 0) {
    float m = red[0];
    for (int i = 1; i < 16; ++i) m = fmaxf(m, red[i]);
    red[0] = m;
  }
  __syncthreads();
  const float m = red[0];
  __syncthreads();
  float sum = 0.f;
#pragma unroll
  for (int s = 0; s < 8; ++s) {
    v[s] = expf(v[s] - m);
    sum += v[s];
  }
#pragma unroll
  for (int off = 32; off > 0; off >>= 1) sum += __shfl_xor(sum, off, 64);
  if (lane == 0) red[wave] = sum;
  __syncthreads();
  if (t == 0) {
    float S = 0.f;
    for (int i = 0; i < 16; ++i) S += red[i];
    red[0] = S;
  }
  __syncthreads();
  const float invS = 1.0f / red[0];
#pragma unroll
  for (int s = 0; s < 8; ++s) wgt[t + 1024 * s] = v[s] * invS;
}

__global__ __launch_bounds__(384) void wsum_kernel(
    const float* __restrict__ wgt, const float* __restrict__ Vt2,
    float* __restrict__ part)
{
  __shared__ float wl[256];
  const int b = blockIdx.x;
  const int t = threadIdx.x;
  if (t < 256) wl[t] = wgt[b * 256 + t];
  __syncthreads();
  const float* Vp = Vt2 + (size_t)b * 256 * kD;
  float acc = 0.f;
  for (int j = 0; j < 256; ++j) acc += wl[j] * Vp[(size_t)j * kD + t];
  part[b * kD + t] = acc;
}

__global__ __launch_bounds__(384) void final_kernel(
    const float* __restrict__ part, const float* __restrict__ ffws,
    float* __restrict__ out)
{
  __shared__ float red[6];
  const int t = threadIdx.x;
  const int wave = t >> 6;
  const int lane = t & 63;
  float z = 0.f;
#pragma unroll
  for (int b = 0; b < 32; ++b) z += part[b * kD + t];
  float val = z * ffws[t];
#pragma unroll
  for (int off = 32; off > 0; off >>= 1) val += __shfl_xor(val, off, 64);
  if (lane == 0) red[wave] = val;
  __syncthreads();
  if (t == 0) {
    float s = red[0];
    for (int i = 1; i < 6; ++i) s += red[i];
    out[0] = 1.0f / (1.0f + expf(-s));
  }
}

// ---------------------------------------------------------------------------
extern "C" void kernel_launch(void* const* d_in, const int* in_sizes, int n_in,
                              void* d_out, int out_size, void* d_ws, size_t ws_size,
                              hipStream_t stream) {
  const float* x    = (const float*)d_in[0];
  const float* Wq   = (const float*)d_in[1];
  const float* Wk   = (const float*)d_in[2];
  const float* Wv   = (const float*)d_in[3];
  const float* ffws = (const float*)d_in[4];
  float* out = (float*)d_out;
  char* wsb = (char*)d_ws;

  ushort* Qh  = (ushort*)wsb;
  ushort* Ql  = Qh + kND;
  ushort* Kh  = Ql + kND;
  ushort* Kl  = Kh + kND;
  ushort* VTh = Kl + kND;
  ushort* VTl = VTh + kND;
  float* Opart = (float*)(wsb + 6 * (size_t)kND * 2);
  float* ml    = Opart + 2 * (size_t)kND;
  // phase-2 overlays (flash buffers dead):
  float* Kt2 = (float*)wsb;                         // over Qh/Ql
  float* Vt2 = (float*)(wsb + 2 * (size_t)kND * 2); // over Kh/Kl
  float* h1  = (float*)(wsb + 4 * (size_t)kND * 2); // over VTh/VTl
  float* q2  = (float*)(wsb + 6 * (size_t)kND * 2); // over Opart
  float* lg  = q2 + kD;
  float* wgt = lg + kN;
  float* part = wgt + kN;

  const dim3 gg(kN / 64, kD / 64);
  gemm_xwT<1><<<gg, 256, 0, stream>>>(x, Wq, nullptr, Qh, Ql);
  gemm_xwT<1><<<gg, 256, 0, stream>>>(x, Wk, nullptr, Kh, Kl);
  gemm_xwT<2><<<gg, 256, 0, stream>>>(x, Wv, nullptr, VTh, VTl);
  flash_mfma<<<dim3(SPLITf, kN / 64), 512, 0, stream>>>(
      Qh, Ql, Kh, Kl, VTh, VTl, Opart, ml);
  merge_kernel<<<(kN * kD) / 256, 256, 0, stream>>>(Opart, ml, h1);
  gemm_xwT<0><<<gg, 256, 0, stream>>>(h1, Wk, Kt2, nullptr, nullptr);
  gemm_xwT<0><<<gg, 256, 0, stream>>>(h1, Wv, Vt2, nullptr, nullptr);
  qrow_kernel<<<kD, 64, 0, stream>>>(h1, Wq, q2);
  logits_kernel<<<kN / 4, 256, 0, stream>>>(Kt2, q2, lg);
  smax_kernel<<<1, 1024, 0, stream>>>(lg, wgt);
  wsum_kernel<<<32, 384, 0, stream>>>(wgt, Vt2, part);
  final_kernel<<<1, 384, 0, stream>>>(part, ffws, out);
}